// Round 2
// baseline (956.814 us; speedup 1.0000x reference)
//
#include <hip/hip_runtime.h>

#define DH 64
#define DIN 32

// ---- edge layout probe: 1 = int32 layout, 0 = int64 (values in low words, stride 2)
__global__ void edge_mode_k(const int* __restrict__ ei, int E, int* __restrict__ flag) {
    __shared__ int any;
    if (threadIdx.x == 0) any = 0;
    __syncthreads();
    int i = threadIdx.x;                       // 256 threads, one block
    int lim = (E < 512) ? E : 512;
    int v = (2 * i + 1 < 2 * lim) ? ei[2 * i + 1] : 0;
    if (v != 0) atomicOr(&any, 1);
    __syncthreads();
    if (threadIdx.x == 0) *flag = any;
}

__global__ void deg_init_k(float* deg, int n) {
    int i = blockIdx.x * blockDim.x + threadIdx.x;
    if (i < n) deg[i] = 1.0f;  // self-loop contributes 1 to every node's degree
}

__global__ void deg_acc_k(const int* __restrict__ ei, const int* __restrict__ flag,
                          float* deg, int E, int n) {
    int e = blockIdx.x * blockDim.x + threadIdx.x;
    if (e >= E) return;
    int m = *flag;                             // wave-uniform scalar load
    const int* dstp = m ? (ei + E) : (ei + 2 * E);
    int d = dstp[(size_t)e * (m ? 1 : 2)];
    if ((unsigned)d < (unsigned)n) atomicAdd(&deg[d], 1.0f);
}

__global__ void dinv_k(float* deg, int n) {
    int i = blockIdx.x * blockDim.x + threadIdx.x;
    if (i < n) deg[i] = rsqrtf(deg[i]);        // deg >= 1 always (self-loops)
}

// h1 = x @ W1 ; out1 = h1 * dinv[n]^2 + b1   (self-loop term + bias pre-seeded)
__global__ void __launch_bounds__(256) gemm1_k(
        const float* __restrict__ x, const float* __restrict__ W1,
        const float* __restrict__ b1, const float* __restrict__ dinv,
        float* __restrict__ h1, float* __restrict__ out1, int n) {
    __shared__ float Wl[DIN * DH];   // 8 KB
    __shared__ float xl[4][DIN];     // 4 nodes per block
    int tid = threadIdx.x;
    for (int i = tid; i < DIN * DH; i += 256) Wl[i] = W1[i];
    if (tid < 4 * DIN) {
        int nn = blockIdx.x * 4 + tid / DIN;
        xl[tid / DIN][tid % DIN] = (nn < n) ? x[(size_t)nn * DIN + tid % DIN] : 0.f;
    }
    __syncthreads();
    int node = blockIdx.x * 4 + (tid >> 6);
    int j = tid & 63;
    if (node < n) {
        const float* xr = xl[tid >> 6];
        float acc = 0.f;
        #pragma unroll
        for (int k = 0; k < DIN; k++) acc += xr[k] * Wl[k * DH + j];
        float di = dinv[node];
        h1[(size_t)node * DH + j] = acc;
        out1[(size_t)node * DH + j] = acc * di * di + b1[j];
    }
}

// Edge aggregation: one wave per edge, lane = feature.
// out[dst][lane] += h[src][lane] * dinv[src]*dinv[dst]
__global__ void __launch_bounds__(256) scatter_k(
        const int* __restrict__ ei, const int* __restrict__ flag,
        const float* __restrict__ dinv, const float* __restrict__ h,
        float* __restrict__ out, int E, int n) {
    int lane = threadIdx.x & 63;
    int e = blockIdx.x * 4 + (threadIdx.x >> 6);
    if (e >= E) return;
    int m = *flag;
    const int* srcp = ei;
    const int* dstp = m ? (ei + E) : (ei + 2 * E);
    int stride = m ? 1 : 2;
    int s = __builtin_amdgcn_readfirstlane(srcp[(size_t)e * stride]);
    int d = __builtin_amdgcn_readfirstlane(dstp[(size_t)e * stride]);
    if ((unsigned)s >= (unsigned)n || (unsigned)d >= (unsigned)n) return;
    float norm = dinv[s] * dinv[d];
    float v = h[(size_t)s * DH + lane] * norm;
    atomicAdd(&out[(size_t)d * DH + lane], v);
}

// h2 = relu(io) @ W2 ; io = h2 * dinv^2 + b2  (in-place over out1; row-local so safe)
__global__ void __launch_bounds__(256) gemm2_k(
        float* __restrict__ io, const float* __restrict__ W2,
        const float* __restrict__ b2, const float* __restrict__ dinv,
        float* __restrict__ h2, int n) {
    __shared__ float Wl[DH * DH];   // 16 KB
    __shared__ float xl[4][DH];     // 1 KB
    int tid = threadIdx.x;
    for (int i = tid; i < DH * DH; i += 256) Wl[i] = W2[i];
    int node = blockIdx.x * 4 + (tid >> 6);
    int j = tid & 63;
    xl[tid >> 6][j] = (node < n) ? fmaxf(io[(size_t)node * DH + j], 0.f) : 0.f;
    __syncthreads();
    if (node < n) {
        const float* xr = xl[tid >> 6];
        float acc = 0.f;
        #pragma unroll
        for (int k = 0; k < DH; k++) acc += xr[k] * Wl[k * DH + j];
        float di = dinv[node];
        h2[(size_t)node * DH + j] = acc;
        io[(size_t)node * DH + j] = acc * di * di + b2[j];
    }
}

// y[n] = sigmoid( relu(out2[n,:]) . Wo + bo )  -- one wave per node
__global__ void __launch_bounds__(256) final_k(
        const float* __restrict__ out2, const float* __restrict__ Wo,
        const float* __restrict__ bo, float* __restrict__ y, int n) {
    int lane = threadIdx.x & 63;
    int node = blockIdx.x * 4 + (threadIdx.x >> 6);
    if (node >= n) return;
    float v = fmaxf(out2[(size_t)node * DH + lane], 0.f) * Wo[lane];
    #pragma unroll
    for (int off = 32; off > 0; off >>= 1) v += __shfl_down(v, off, 64);
    if (lane == 0) {
        float z = v + bo[0];
        float s = 1.f / (1.f + __expf(-z));
        y[node] = s;
    }
}

extern "C" void kernel_launch(void* const* d_in, const int* in_sizes, int n_in,
                              void* d_out, int out_size, void* d_ws, size_t ws_size,
                              hipStream_t stream) {
    const float* x  = (const float*)d_in[0];
    const int*   ei = (const int*)d_in[1];
    const float* W1 = (const float*)d_in[2];
    const float* b1 = (const float*)d_in[3];
    const float* W2 = (const float*)d_in[4];
    const float* b2 = (const float*)d_in[5];
    const float* Wo = (const float*)d_in[6];
    const float* bo = (const float*)d_in[7];
    float* y = (float*)d_out;

    int N = in_sizes[0] / DIN;
    int E = in_sizes[1] / 2;

    char* ws = (char*)d_ws;
    size_t off = 0;
    int*   flag = (int*)(ws + off);   off += 256;
    float* dinv = (float*)(ws + off); off += (((size_t)N * 4) + 255) & ~(size_t)255;
    float* bufA = (float*)(ws + off); off += (((size_t)N * DH * 4) + 255) & ~(size_t)255;
    float* bufB = (float*)(ws + off);
    // total ws use: ~0.4MB + 2*25.6MB = ~51.6MB

    int gN = (N + 255) / 256;
    int gE = (E + 255) / 256;
    int gN4 = (N + 3) / 4;
    int gE4 = (E + 3) / 4;

    edge_mode_k<<<1, 256, 0, stream>>>(ei, E, flag);
    deg_init_k<<<gN, 256, 0, stream>>>(dinv, N);
    deg_acc_k<<<gE, 256, 0, stream>>>(ei, flag, dinv, E, N);
    dinv_k<<<gN, 256, 0, stream>>>(dinv, N);

    // layer 1: bufA = h1, bufB = out1 (seeded with self-loop + bias)
    gemm1_k<<<gN4, 256, 0, stream>>>(x, W1, b1, dinv, bufA, bufB, N);
    scatter_k<<<gE4, 256, 0, stream>>>(ei, flag, dinv, bufA, bufB, E, N);

    // layer 2: bufA = h2 (reuses h1 space), bufB = out2 (in-place over out1)
    gemm2_k<<<gN4, 256, 0, stream>>>(bufB, W2, b2, dinv, bufA, N);
    scatter_k<<<gE4, 256, 0, stream>>>(ei, flag, dinv, bufA, bufB, E, N);

    // head
    final_k<<<gN4, 256, 0, stream>>>(bufB, Wo, bo, y, N);
}

// Round 3
// 571.052 us; speedup vs baseline: 1.6755x; 1.6755x over previous
//
#include <hip/hip_runtime.h>

#define DH 64
#define DIN 32

// ---- edge layout probe: 1 = int32 layout, 0 = int64 (values in low words, stride 2)
__global__ void edge_mode_k(const int* __restrict__ ei, int E, int* __restrict__ flag) {
    __shared__ int any;
    if (threadIdx.x == 0) any = 0;
    __syncthreads();
    int i = threadIdx.x;                       // 256 threads, one block
    int lim = (E < 512) ? E : 512;
    int v = (2 * i + 1 < 2 * lim) ? ei[2 * i + 1] : 0;
    if (v != 0) atomicOr(&any, 1);
    __syncthreads();
    if (threadIdx.x == 0) *flag = any;
}

// cnt[d]++ for each edge (cnt pre-zeroed via hipMemsetAsync)
__global__ void hist_k(const int* __restrict__ ei, const int* __restrict__ flag,
                       int* __restrict__ cnt, int E, int n) {
    int e = blockIdx.x * blockDim.x + threadIdx.x;
    if (e >= E) return;
    int m = *flag;
    const int* dstp = m ? (ei + E) : (ei + 2 * E);
    int d = dstp[(size_t)e * (m ? 1 : 2)];
    if ((unsigned)d < (unsigned)n) atomicAdd(&cnt[d], 1);
}

// block-level exclusive scan: 1024 counts per block (256 thr x 4)
__global__ void __launch_bounds__(256) scan1_k(const int* __restrict__ cnt,
                                               int* __restrict__ rowptr,
                                               int* __restrict__ partials, int N) {
    __shared__ int s[256];
    int t = threadIdx.x;
    int base = blockIdx.x * 1024 + t * 4;
    int v0 = (base + 0 < N) ? cnt[base + 0] : 0;
    int v1 = (base + 1 < N) ? cnt[base + 1] : 0;
    int v2 = (base + 2 < N) ? cnt[base + 2] : 0;
    int v3 = (base + 3 < N) ? cnt[base + 3] : 0;
    int tot = v0 + v1 + v2 + v3;
    s[t] = tot;
    __syncthreads();
    for (int off = 1; off < 256; off <<= 1) {
        int x = (t >= off) ? s[t - off] : 0;
        __syncthreads();
        s[t] += x;
        __syncthreads();
    }
    int excl = s[t] - tot;
    if (t == 255) partials[blockIdx.x] = s[255];
    if (base + 0 < N) rowptr[base + 0] = excl;
    if (base + 1 < N) rowptr[base + 1] = excl + v0;
    if (base + 2 < N) rowptr[base + 2] = excl + v0 + v1;
    if (base + 3 < N) rowptr[base + 3] = excl + v0 + v1 + v2;
}

// scan the per-block partials (nb <= 256), write grand total to rowptr[N]
__global__ void __launch_bounds__(256) scan2_k(int* __restrict__ partials,
                                               int* __restrict__ rowptr_end, int nb) {
    __shared__ int s[256];
    int t = threadIdx.x;
    int v = (t < nb) ? partials[t] : 0;
    s[t] = v;
    __syncthreads();
    for (int off = 1; off < 256; off <<= 1) {
        int x = (t >= off) ? s[t - off] : 0;
        __syncthreads();
        s[t] += x;
        __syncthreads();
    }
    if (t < nb) partials[t] = s[t] - v;
    if (t == 255) *rowptr_end = s[255];
}

// finalize rowptr, copy to cursor, derive dinv from counts (deg = cnt + 1 self-loop)
__global__ void scan3_k(int* __restrict__ rowptr, int* __restrict__ cursor,
                        const int* __restrict__ partials, float* __restrict__ dinv, int N) {
    int i = blockIdx.x * blockDim.x + threadIdx.x;
    if (i >= N) return;
    int c = cursor[i];                 // original count (cursor buffer == cnt buffer)
    int r = rowptr[i] + partials[i >> 10];
    rowptr[i] = r;
    cursor[i] = r;
    dinv[i] = rsqrtf((float)c + 1.0f);
}

// col[pos] = src for each edge, bucketed by dst
__global__ void fill_k(const int* __restrict__ ei, const int* __restrict__ flag,
                       int* __restrict__ cursor, int* __restrict__ col, int E, int n) {
    int e = blockIdx.x * blockDim.x + threadIdx.x;
    if (e >= E) return;
    int m = *flag;
    const int* srcp = ei;
    const int* dstp = m ? (ei + E) : (ei + 2 * E);
    int stride = m ? 1 : 2;
    int s = srcp[(size_t)e * stride];
    int d = dstp[(size_t)e * stride];
    if ((unsigned)s >= (unsigned)n || (unsigned)d >= (unsigned)n) return;
    int pos = atomicAdd(&cursor[d], 1);
    col[pos] = s;
}

// h1' = (x @ W1) * dinv[node]
__global__ void __launch_bounds__(256) gemm1_k(
        const float* __restrict__ x, const float* __restrict__ W1,
        const float* __restrict__ dinv, float* __restrict__ hp, int n) {
    __shared__ float Wl[DIN * DH];   // 8 KB
    __shared__ float xl[4][DIN];
    int tid = threadIdx.x;
    for (int i = tid; i < DIN * DH; i += 256) Wl[i] = W1[i];
    if (tid < 4 * DIN) {
        int nn = blockIdx.x * 4 + tid / DIN;
        xl[tid / DIN][tid % DIN] = (nn < n) ? x[(size_t)nn * DIN + tid % DIN] : 0.f;
    }
    __syncthreads();
    int node = blockIdx.x * 4 + (tid >> 6);
    int j = tid & 63;
    if (node < n) {
        const float* xr = xl[tid >> 6];
        float acc = 0.f;
        #pragma unroll
        for (int k = 0; k < DIN; k++) acc += xr[k] * Wl[k * DH + j];
        hp[(size_t)node * DH + j] = acc * dinv[node];
    }
}

// gather-aggregate: out[d] = (h'[d] + sum_{s in N(d)} h'[s]) * dinv[d] + bias
__global__ void __launch_bounds__(256) agg_k(
        const float* __restrict__ hp, const int* __restrict__ rowptr,
        const int* __restrict__ col, const float* __restrict__ dinv,
        const float* __restrict__ bias, float* __restrict__ out, int N) {
    int lane = threadIdx.x & 63;
    int node = blockIdx.x * 4 + (threadIdx.x >> 6);
    if (node >= N) return;
    int start = __builtin_amdgcn_readfirstlane(rowptr[node]);
    int end   = __builtin_amdgcn_readfirstlane(rowptr[node + 1]);
    float acc = hp[(size_t)node * DH + lane];          // self-loop term
    for (int i = start; i < end; i += 64) {
        int m = end - i; if (m > 64) m = 64;
        int cbuf = (lane < m) ? col[i + lane] : 0;
        for (int j = 0; j < m; ++j) {
            int c = __shfl(cbuf, j, 64);
            acc += hp[(size_t)c * DH + lane];
        }
    }
    out[(size_t)node * DH + lane] = acc * dinv[node] + bias[lane];
}

// h2' = (relu(io) @ W2) * dinv[node]
__global__ void __launch_bounds__(256) gemm2_k(
        const float* __restrict__ io, const float* __restrict__ W2,
        const float* __restrict__ dinv, float* __restrict__ hp, int n) {
    __shared__ float Wl[DH * DH];   // 16 KB
    __shared__ float xl[4][DH];
    int tid = threadIdx.x;
    for (int i = tid; i < DH * DH; i += 256) Wl[i] = W2[i];
    int node = blockIdx.x * 4 + (tid >> 6);
    int j = tid & 63;
    xl[tid >> 6][j] = (node < n) ? fmaxf(io[(size_t)node * DH + j], 0.f) : 0.f;
    __syncthreads();
    if (node < n) {
        const float* xr = xl[tid >> 6];
        float acc = 0.f;
        #pragma unroll
        for (int k = 0; k < DH; k++) acc += xr[k] * Wl[k * DH + j];
        hp[(size_t)node * DH + j] = acc * dinv[node];
    }
}

// y[n] = sigmoid( relu(out2[n,:]) . Wo + bo )  -- one wave per node
__global__ void __launch_bounds__(256) final_k(
        const float* __restrict__ out2, const float* __restrict__ Wo,
        const float* __restrict__ bo, float* __restrict__ y, int n) {
    int lane = threadIdx.x & 63;
    int node = blockIdx.x * 4 + (threadIdx.x >> 6);
    if (node >= n) return;
    float v = fmaxf(out2[(size_t)node * DH + lane], 0.f) * Wo[lane];
    #pragma unroll
    for (int off = 32; off > 0; off >>= 1) v += __shfl_down(v, off, 64);
    if (lane == 0) {
        float z = v + bo[0];
        float s = 1.f / (1.f + __expf(-z));
        y[node] = s;
    }
}

extern "C" void kernel_launch(void* const* d_in, const int* in_sizes, int n_in,
                              void* d_out, int out_size, void* d_ws, size_t ws_size,
                              hipStream_t stream) {
    const float* x  = (const float*)d_in[0];
    const int*   ei = (const int*)d_in[1];
    const float* W1 = (const float*)d_in[2];
    const float* b1 = (const float*)d_in[3];
    const float* W2 = (const float*)d_in[4];
    const float* b2 = (const float*)d_in[5];
    const float* Wo = (const float*)d_in[6];
    const float* bo = (const float*)d_in[7];
    float* y = (float*)d_out;

    int N = in_sizes[0] / DIN;
    int E = in_sizes[1] / 2;

    char* ws = (char*)d_ws;
    size_t off = 0;
    auto alloc = [&](size_t bytes) { char* p = ws + off; off += (bytes + 255) & ~(size_t)255; return p; };
    int*   flag     = (int*)alloc(4);
    int*   cursor   = (int*)alloc((size_t)N * 4);          // doubles as cnt
    int*   rowptr   = (int*)alloc(((size_t)N + 1) * 4);
    int*   partials = (int*)alloc(256 * 4);
    float* dinv     = (float*)alloc((size_t)N * 4);
    int*   col      = (int*)alloc((size_t)E * 4);
    float* bufA     = (float*)alloc((size_t)N * DH * 4);
    float* bufB     = (float*)alloc((size_t)N * DH * 4);
    // total ~58.8 MB

    int gN  = (N + 255) / 256;
    int gE  = (E + 255) / 256;
    int gN4 = (N + 3) / 4;
    int nb  = (N + 1023) / 1024;   // <= 256 for N <= 262144

    edge_mode_k<<<1, 256, 0, stream>>>(ei, E, flag);
    hipMemsetAsync(cursor, 0, (size_t)N * 4, stream);
    hist_k<<<gE, 256, 0, stream>>>(ei, flag, cursor, E, N);
    scan1_k<<<nb, 256, 0, stream>>>(cursor, rowptr, partials, N);
    scan2_k<<<1, 256, 0, stream>>>(partials, rowptr + N, nb);
    scan3_k<<<gN, 256, 0, stream>>>(rowptr, cursor, partials, dinv, N);
    fill_k<<<gE, 256, 0, stream>>>(ei, flag, cursor, col, E, N);

    // layer 1
    gemm1_k<<<gN4, 256, 0, stream>>>(x, W1, dinv, bufA, N);
    agg_k<<<gN4, 256, 0, stream>>>(bufA, rowptr, col, dinv, b1, bufB, N);

    // layer 2
    gemm2_k<<<gN4, 256, 0, stream>>>(bufB, W2, dinv, bufA, N);
    agg_k<<<gN4, 256, 0, stream>>>(bufA, rowptr, col, dinv, b2, bufB, N);

    // head
    final_k<<<gN4, 256, 0, stream>>>(bufB, Wo, bo, y, N);
}

// Round 4
// 429.277 us; speedup vs baseline: 2.2289x; 1.3303x over previous
//
#include <hip/hip_runtime.h>

#define DH 64
#define DIN 32

// ---- edge layout probe: 1 = int32 layout, 0 = int64 (values in low words, stride 2)
__global__ void edge_mode_k(const int* __restrict__ ei, int E, int* __restrict__ flag) {
    __shared__ int any;
    if (threadIdx.x == 0) any = 0;
    __syncthreads();
    int i = threadIdx.x;                       // 256 threads, one block
    int lim = (E < 512) ? E : 512;
    int v = (2 * i + 1 < 2 * lim) ? ei[2 * i + 1] : 0;
    if (v != 0) atomicOr(&any, 1);
    __syncthreads();
    if (threadIdx.x == 0) *flag = any;
}

// cnt[d]++ for each edge (cnt pre-zeroed via hipMemsetAsync)
__global__ void hist_k(const int* __restrict__ ei, const int* __restrict__ flag,
                       int* __restrict__ cnt, int E, int n) {
    int e = blockIdx.x * blockDim.x + threadIdx.x;
    if (e >= E) return;
    int m = *flag;
    const int* dstp = m ? (ei + E) : (ei + 2 * E);
    int d = dstp[(size_t)e * (m ? 1 : 2)];
    if ((unsigned)d < (unsigned)n) atomicAdd(&cnt[d], 1);
}

// block-level exclusive scan: 1024 counts per block (256 thr x 4)
__global__ void __launch_bounds__(256) scan1_k(const int* __restrict__ cnt,
                                               int* __restrict__ rowptr,
                                               int* __restrict__ partials, int N) {
    __shared__ int s[256];
    int t = threadIdx.x;
    int base = blockIdx.x * 1024 + t * 4;
    int v0 = (base + 0 < N) ? cnt[base + 0] : 0;
    int v1 = (base + 1 < N) ? cnt[base + 1] : 0;
    int v2 = (base + 2 < N) ? cnt[base + 2] : 0;
    int v3 = (base + 3 < N) ? cnt[base + 3] : 0;
    int tot = v0 + v1 + v2 + v3;
    s[t] = tot;
    __syncthreads();
    for (int off = 1; off < 256; off <<= 1) {
        int x = (t >= off) ? s[t - off] : 0;
        __syncthreads();
        s[t] += x;
        __syncthreads();
    }
    int excl = s[t] - tot;
    if (t == 255) partials[blockIdx.x] = s[255];
    if (base + 0 < N) rowptr[base + 0] = excl;
    if (base + 1 < N) rowptr[base + 1] = excl + v0;
    if (base + 2 < N) rowptr[base + 2] = excl + v0 + v1;
    if (base + 3 < N) rowptr[base + 3] = excl + v0 + v1 + v2;
}

// scan the per-block partials (nb <= 256), write grand total to rowptr[N]
__global__ void __launch_bounds__(256) scan2_k(int* __restrict__ partials,
                                               int* __restrict__ rowptr_end, int nb) {
    __shared__ int s[256];
    int t = threadIdx.x;
    int v = (t < nb) ? partials[t] : 0;
    s[t] = v;
    __syncthreads();
    for (int off = 1; off < 256; off <<= 1) {
        int x = (t >= off) ? s[t - off] : 0;
        __syncthreads();
        s[t] += x;
        __syncthreads();
    }
    if (t < nb) partials[t] = s[t] - v;
    if (t == 255) *rowptr_end = s[255];
}

// finalize rowptr, copy to cursor, derive dinv from counts (deg = cnt + 1 self-loop)
__global__ void scan3_k(int* __restrict__ rowptr, int* __restrict__ cursor,
                        const int* __restrict__ partials, float* __restrict__ dinv, int N) {
    int i = blockIdx.x * blockDim.x + threadIdx.x;
    if (i >= N) return;
    int c = cursor[i];                 // original count (cursor buffer == cnt buffer)
    int r = rowptr[i] + partials[i >> 10];
    rowptr[i] = r;
    cursor[i] = r;
    dinv[i] = rsqrtf((float)c + 1.0f);
}

// col[pos] = src for each edge, bucketed by dst
__global__ void fill_k(const int* __restrict__ ei, const int* __restrict__ flag,
                       int* __restrict__ cursor, int* __restrict__ col, int E, int n) {
    int e = blockIdx.x * blockDim.x + threadIdx.x;
    if (e >= E) return;
    int m = *flag;
    const int* srcp = ei;
    const int* dstp = m ? (ei + E) : (ei + 2 * E);
    int stride = m ? 1 : 2;
    int s = srcp[(size_t)e * stride];
    int d = dstp[(size_t)e * stride];
    if ((unsigned)s >= (unsigned)n || (unsigned)d >= (unsigned)n) return;
    int pos = atomicAdd(&cursor[d], 1);
    col[pos] = s;
}

// h1' = (x @ W1) * dinv[node]; 16 nodes/block, wave = 4 nodes x 16 lanes x float4
__global__ void __launch_bounds__(256) gemm1_k(
        const float* __restrict__ x, const float* __restrict__ W1,
        const float* __restrict__ dinv, float* __restrict__ hp, int n) {
    __shared__ float Wl[DIN * DH];           // 8 KB, layout Wl[k*64 + j]
    __shared__ float xl[16][DIN + 4];        // +4 pad: conflict-free group-broadcast reads
    int tid = threadIdx.x;
    {   // W1: 2048 floats = 512 float4
        const float4* Wv = (const float4*)W1;
        float4* Wd = (float4*)Wl;
        Wd[tid] = Wv[tid];
        Wd[tid + 256] = Wv[tid + 256];
    }
    if (tid < 128) {                          // x tile: 16*32 floats = 128 float4
        int idx = tid * 4;
        int row = idx / DIN, ck = idx % DIN;
        float4 v = {0.f, 0.f, 0.f, 0.f};
        if (blockIdx.x * 16 + row < n)
            v = *(const float4*)&x[(size_t)blockIdx.x * 16 * DIN + idx];
        *(float4*)&xl[row][ck] = v;           // row stride 36 floats = 144 B, 16B-aligned
    }
    __syncthreads();
    int lane = tid & 63, w = tid >> 6;
    int g = lane >> 4, c = lane & 15;
    int node = blockIdx.x * 16 + w * 4 + g;
    const float* xr = xl[w * 4 + g];
    float4 acc = {0.f, 0.f, 0.f, 0.f};
    #pragma unroll
    for (int k = 0; k < DIN; k++) {
        float xv = xr[k];
        float4 wv = *(const float4*)&Wl[k * DH + c * 4];
        acc.x += xv * wv.x; acc.y += xv * wv.y; acc.z += xv * wv.z; acc.w += xv * wv.w;
    }
    if (node < n) {
        float di = dinv[node];
        acc.x *= di; acc.y *= di; acc.z *= di; acc.w *= di;
        *(float4*)&hp[(size_t)node * DH + c * 4] = acc;
    }
}

// h2' = (relu(io) @ W2) * dinv[node]; same structure, K=64
__global__ void __launch_bounds__(256) gemm2_k(
        const float* __restrict__ io, const float* __restrict__ W2,
        const float* __restrict__ dinv, float* __restrict__ hp, int n) {
    __shared__ float Wl[DH * DH];            // 16 KB
    __shared__ float xl[16][DH + 4];         // pad 68 floats = 272 B rows (16B-aligned)
    int tid = threadIdx.x;
    {   // W2: 4096 floats = 1024 float4
        const float4* Wv = (const float4*)W2;
        float4* Wd = (float4*)Wl;
        #pragma unroll
        for (int r = 0; r < 4; r++) Wd[tid + 256 * r] = Wv[tid + 256 * r];
    }
    {   // io tile: 16*64 floats = 256 float4, with relu
        int idx = tid * 4;
        int row = idx / DH, ck = idx % DH;
        float4 v = {0.f, 0.f, 0.f, 0.f};
        if (blockIdx.x * 16 + row < n) {
            v = *(const float4*)&io[(size_t)blockIdx.x * 16 * DH + idx];
            v.x = fmaxf(v.x, 0.f); v.y = fmaxf(v.y, 0.f);
            v.z = fmaxf(v.z, 0.f); v.w = fmaxf(v.w, 0.f);
        }
        *(float4*)&xl[row][ck] = v;
    }
    __syncthreads();
    int lane = tid & 63, w = tid >> 6;
    int g = lane >> 4, c = lane & 15;
    int node = blockIdx.x * 16 + w * 4 + g;
    const float* xr = xl[w * 4 + g];
    float4 acc = {0.f, 0.f, 0.f, 0.f};
    #pragma unroll
    for (int k = 0; k < DH; k++) {
        float xv = xr[k];
        float4 wv = *(const float4*)&Wl[k * DH + c * 4];
        acc.x += xv * wv.x; acc.y += xv * wv.y; acc.z += xv * wv.z; acc.w += xv * wv.w;
    }
    if (node < n) {
        float di = dinv[node];
        acc.x *= di; acc.y *= di; acc.z *= di; acc.w *= di;
        *(float4*)&hp[(size_t)node * DH + c * 4] = acc;
    }
}

// shared edge-sum core: wave = 1 node; lane -> group g=lane>>4 (edge slot), c=lane&15 (float4 cols)
__device__ __forceinline__ float4 edge_sum(const float* __restrict__ hp,
                                           const int* __restrict__ rowptr,
                                           const int* __restrict__ col,
                                           int node, int g, int c) {
    int start = __builtin_amdgcn_readfirstlane(rowptr[node]);
    int end   = __builtin_amdgcn_readfirstlane(rowptr[node + 1]);
    int lane  = (g << 4) | c;
    float4 acc = {0.f, 0.f, 0.f, 0.f};
    for (int base = start; base < end; base += 64) {
        int rem = end - base; if (rem > 64) rem = 64;
        int cb = (lane < rem) ? col[base + lane] : 0;
        for (int jj = 0; jj < rem; jj += 8) {
            int e0 = jj + g, e1 = jj + 4 + g;
            int s0 = __shfl(cb, e0, 64);
            int s1 = __shfl(cb, e1, 64);
            bool a0 = e0 < rem, a1 = e1 < rem;
            if (a0) {
                float4 v = *(const float4*)&hp[(size_t)s0 * DH + c * 4];
                acc.x += v.x; acc.y += v.y; acc.z += v.z; acc.w += v.w;
            }
            if (a1) {
                float4 v = *(const float4*)&hp[(size_t)s1 * DH + c * 4];
                acc.x += v.x; acc.y += v.y; acc.z += v.z; acc.w += v.w;
            }
        }
    }
    // combine the 4 edge-groups: after this every lane holds the full sum
    #pragma unroll
    for (int m = 16; m <= 32; m <<= 1) {
        acc.x += __shfl_xor(acc.x, m, 64);
        acc.y += __shfl_xor(acc.y, m, 64);
        acc.z += __shfl_xor(acc.z, m, 64);
        acc.w += __shfl_xor(acc.w, m, 64);
    }
    return acc;
}

// out[d] = (h'[d] + sum_{s in N(d)} h'[s]) * dinv[d] + bias
__global__ void __launch_bounds__(256) agg_mid_k(
        const float* __restrict__ hp, const int* __restrict__ rowptr,
        const int* __restrict__ col, const float* __restrict__ dinv,
        const float* __restrict__ bias, float* __restrict__ out, int N) {
    int lane = threadIdx.x & 63;
    int node = blockIdx.x * 4 + (threadIdx.x >> 6);
    if (node >= N) return;
    int g = lane >> 4, c = lane & 15;
    float4 acc = edge_sum(hp, rowptr, col, node, g, c);
    if (g == 0) {
        float4 self = *(const float4*)&hp[(size_t)node * DH + c * 4];
        float4 b = *(const float4*)&bias[c * 4];
        float di = dinv[node];
        float4 o;
        o.x = (acc.x + self.x) * di + b.x;
        o.y = (acc.y + self.y) * di + b.y;
        o.z = (acc.z + self.z) * di + b.z;
        o.w = (acc.w + self.w) * di + b.w;
        *(float4*)&out[(size_t)node * DH + c * 4] = o;
    }
}

// fused layer-2 aggregation + head: y = sigmoid(relu(out2) . Wo + bo), out2 never stored
__global__ void __launch_bounds__(256) agg_head_k(
        const float* __restrict__ hp, const int* __restrict__ rowptr,
        const int* __restrict__ col, const float* __restrict__ dinv,
        const float* __restrict__ bias, const float* __restrict__ Wo,
        const float* __restrict__ bo, float* __restrict__ y, int N) {
    int lane = threadIdx.x & 63;
    int node = blockIdx.x * 4 + (threadIdx.x >> 6);
    if (node >= N) return;
    int g = lane >> 4, c = lane & 15;
    float4 acc = edge_sum(hp, rowptr, col, node, g, c);
    if (g == 0) {
        float4 self = *(const float4*)&hp[(size_t)node * DH + c * 4];
        float4 b = *(const float4*)&bias[c * 4];
        float4 wo = *(const float4*)&Wo[c * 4];
        float di = dinv[node];
        float t = fmaxf((acc.x + self.x) * di + b.x, 0.f) * wo.x
                + fmaxf((acc.y + self.y) * di + b.y, 0.f) * wo.y
                + fmaxf((acc.z + self.z) * di + b.z, 0.f) * wo.z
                + fmaxf((acc.w + self.w) * di + b.w, 0.f) * wo.w;
        #pragma unroll
        for (int m = 1; m < 16; m <<= 1) t += __shfl_xor(t, m, 64);
        if (c == 0) {
            float z = t + bo[0];
            y[node] = 1.f / (1.f + __expf(-z));
        }
    }
}

extern "C" void kernel_launch(void* const* d_in, const int* in_sizes, int n_in,
                              void* d_out, int out_size, void* d_ws, size_t ws_size,
                              hipStream_t stream) {
    const float* x  = (const float*)d_in[0];
    const int*   ei = (const int*)d_in[1];
    const float* W1 = (const float*)d_in[2];
    const float* b1 = (const float*)d_in[3];
    const float* W2 = (const float*)d_in[4];
    const float* b2 = (const float*)d_in[5];
    const float* Wo = (const float*)d_in[6];
    const float* bo = (const float*)d_in[7];
    float* y = (float*)d_out;

    int N = in_sizes[0] / DIN;
    int E = in_sizes[1] / 2;

    char* ws = (char*)d_ws;
    size_t off = 0;
    auto alloc = [&](size_t bytes) { char* p = ws + off; off += (bytes + 255) & ~(size_t)255; return p; };
    int*   flag     = (int*)alloc(4);
    int*   cursor   = (int*)alloc((size_t)N * 4);          // doubles as cnt
    int*   rowptr   = (int*)alloc(((size_t)N + 1) * 4);
    int*   partials = (int*)alloc(256 * 4);
    float* dinv     = (float*)alloc((size_t)N * 4);
    int*   col      = (int*)alloc((size_t)E * 4);
    float* bufA     = (float*)alloc((size_t)N * DH * 4);
    float* bufB     = (float*)alloc((size_t)N * DH * 4);

    int gN   = (N + 255) / 256;
    int gE   = (E + 255) / 256;
    int gN4  = (N + 3) / 4;
    int gN16 = (N + 15) / 16;
    int nb   = (N + 1023) / 1024;   // <= 256 for N <= 262144

    edge_mode_k<<<1, 256, 0, stream>>>(ei, E, flag);
    hipMemsetAsync(cursor, 0, (size_t)N * 4, stream);
    hist_k<<<gE, 256, 0, stream>>>(ei, flag, cursor, E, N);
    scan1_k<<<nb, 256, 0, stream>>>(cursor, rowptr, partials, N);
    scan2_k<<<1, 256, 0, stream>>>(partials, rowptr + N, nb);
    scan3_k<<<gN, 256, 0, stream>>>(rowptr, cursor, partials, dinv, N);
    fill_k<<<gE, 256, 0, stream>>>(ei, flag, cursor, col, E, N);

    // layer 1
    gemm1_k<<<gN16, 256, 0, stream>>>(x, W1, dinv, bufA, N);
    agg_mid_k<<<gN4, 256, 0, stream>>>(bufA, rowptr, col, dinv, b1, bufB, N);

    // layer 2 + fused head
    gemm2_k<<<gN16, 256, 0, stream>>>(bufB, W2, dinv, bufA, N);
    agg_head_k<<<gN4, 256, 0, stream>>>(bufA, rowptr, col, dinv, b2, Wo, bo, y, N);
}

// Round 5
// 378.814 us; speedup vs baseline: 2.5258x; 1.1332x over previous
//
#include <hip/hip_runtime.h>

#define DH 64
#define DIN 32
#define BSH 11            // bucket = dst >> 11 (2048-node ranges)
#define MAXB 1024

typedef unsigned short u16;

__device__ __forceinline__ float bf2f(u16 u) {
    union { unsigned int i; float f; } x; x.i = ((unsigned int)u) << 16; return x.f;
}
__device__ __forceinline__ u16 f2bf(float f) {
    union { float f; unsigned int i; } x; x.f = f;
    unsigned int r = x.i + 0x7fff + ((x.i >> 16) & 1);   // round-to-nearest-even
    return (u16)(r >> 16);
}

// ---- edge layout probe: 1 = int32 layout, 0 = int64 (values in low words, stride 2)
__global__ void edge_mode_k(const int* __restrict__ ei, int E, int* __restrict__ flag) {
    __shared__ int any;
    if (threadIdx.x == 0) any = 0;
    __syncthreads();
    int i = threadIdx.x;
    int lim = (E < 512) ? E : 512;
    int v = (2 * i + 1 < 2 * lim) ? ei[2 * i + 1] : 0;
    if (v != 0) atomicOr(&any, 1);
    __syncthreads();
    if (threadIdx.x == 0) *flag = any;
}

// cnt[d]++ for each edge (cnt pre-zeroed via hipMemsetAsync)
__global__ void hist_k(const int* __restrict__ ei, const int* __restrict__ flag,
                       int* __restrict__ cnt, int E, int n) {
    int e = blockIdx.x * blockDim.x + threadIdx.x;
    if (e >= E) return;
    int m = *flag;
    const int* dstp = m ? (ei + E) : (ei + 2 * E);
    int d = dstp[(size_t)e * (m ? 1 : 2)];
    if ((unsigned)d < (unsigned)n) atomicAdd(&cnt[d], 1);
}

// block-level exclusive scan: 1024 counts per block (256 thr x 4)
__global__ void __launch_bounds__(256) scan1_k(const int* __restrict__ cnt,
                                               int* __restrict__ rowptr,
                                               int* __restrict__ partials, int N) {
    __shared__ int s[256];
    int t = threadIdx.x;
    int base = blockIdx.x * 1024 + t * 4;
    int v0 = (base + 0 < N) ? cnt[base + 0] : 0;
    int v1 = (base + 1 < N) ? cnt[base + 1] : 0;
    int v2 = (base + 2 < N) ? cnt[base + 2] : 0;
    int v3 = (base + 3 < N) ? cnt[base + 3] : 0;
    int tot = v0 + v1 + v2 + v3;
    s[t] = tot;
    __syncthreads();
    for (int off = 1; off < 256; off <<= 1) {
        int x = (t >= off) ? s[t - off] : 0;
        __syncthreads();
        s[t] += x;
        __syncthreads();
    }
    int excl = s[t] - tot;
    if (t == 255) partials[blockIdx.x] = s[255];
    if (base + 0 < N) rowptr[base + 0] = excl;
    if (base + 1 < N) rowptr[base + 1] = excl + v0;
    if (base + 2 < N) rowptr[base + 2] = excl + v0 + v1;
    if (base + 3 < N) rowptr[base + 3] = excl + v0 + v1 + v2;
}

__global__ void __launch_bounds__(256) scan2_k(int* __restrict__ partials,
                                               int* __restrict__ rowptr_end, int nb) {
    __shared__ int s[256];
    int t = threadIdx.x;
    int v = (t < nb) ? partials[t] : 0;
    s[t] = v;
    __syncthreads();
    for (int off = 1; off < 256; off <<= 1) {
        int x = (t >= off) ? s[t - off] : 0;
        __syncthreads();
        s[t] += x;
        __syncthreads();
    }
    if (t < nb) partials[t] = s[t] - v;
    if (t == 255) *rowptr_end = s[255];
}

// finalize rowptr, copy to cursor, derive dinv (deg = cnt + 1 self-loop)
__global__ void scan3_k(int* __restrict__ rowptr, int* __restrict__ cursor,
                        const int* __restrict__ partials, float* __restrict__ dinv, int N) {
    int i = blockIdx.x * blockDim.x + threadIdx.x;
    if (i >= N) return;
    int c = cursor[i];
    int r = rowptr[i] + partials[i >> 10];
    rowptr[i] = r;
    cursor[i] = r;
    dinv[i] = rsqrtf((float)c + 1.0f);
}

// per-bucket global cursors = rowptr at bucket boundaries
__global__ void initgcur_k(const int* __restrict__ rowptr, int* __restrict__ gcur,
                           int nbuck, int N) {
    int b = blockIdx.x * blockDim.x + threadIdx.x;
    if (b >= nbuck) return;
    int node = b << BSH; if (node > N) node = N;
    gcur[b] = rowptr[node];
}

// Pass A: bin (src,dst) pairs into bucket-contiguous pairs[] with per-(block,bucket)
// private spans -> all partial-line writes come from ONE L2 each, no amplification.
__global__ void __launch_bounds__(256) binA_k(
        const int* __restrict__ ei, const int* __restrict__ flag,
        int* __restrict__ gcur, uint2* __restrict__ pairs, int E, int n, int nbuck) {
    __shared__ int lhist[MAXB];
    __shared__ int lbase[MAXB];
    int t = threadIdx.x;
    for (int b = t; b < nbuck; b += 256) lhist[b] = 0;
    __syncthreads();

    int m = *flag;
    const int* srcp = ei;
    const int* dstp = m ? (ei + E) : (ei + 2 * E);
    int stride = m ? 1 : 2;

    int chunk = (E + gridDim.x - 1) / gridDim.x;
    int lo = blockIdx.x * chunk;
    int hi = lo + chunk; if (hi > E) hi = E;

    // phase 1: count this block's edges per bucket
    for (int e = lo + t; e < hi; e += 256) {
        int d = dstp[(size_t)e * stride];
        if ((unsigned)d < (unsigned)n) atomicAdd(&lhist[d >> BSH], 1);
    }
    __syncthreads();
    // phase 2: reserve private spans
    for (int b = t; b < nbuck; b += 256) {
        int c = lhist[b];
        lbase[b] = c ? atomicAdd(&gcur[b], c) : 0;
        lhist[b] = 0;                       // reuse as local cursor
    }
    __syncthreads();
    // phase 3: scatter into private spans
    for (int e = lo + t; e < hi; e += 256) {
        int d = dstp[(size_t)e * stride];
        if ((unsigned)d >= (unsigned)n) continue;
        int s = srcp[(size_t)e * stride];
        if ((unsigned)s >= (unsigned)n) s = 0;   // keep slot (consistent with hist)
        int b = d >> BSH;
        int off = atomicAdd(&lhist[b], 1);
        pairs[lbase[b] + off] = make_uint2((unsigned)s, (unsigned)d);
    }
}

// Pass B: pairs -> col within each bucket (2 blocks/bucket; writes stay in <=2 L2s)
__global__ void __launch_bounds__(256) fillB_k(
        const uint2* __restrict__ pairs, const int* __restrict__ rowptr,
        int* __restrict__ cursor, int* __restrict__ col, int N) {
    int b = blockIdx.x >> 1;
    int half = blockIdx.x & 1;
    int n0 = b << BSH;       if (n0 > N) n0 = N;
    int n1 = (b + 1) << BSH; if (n1 > N) n1 = N;
    int lo = rowptr[n0], hi = rowptr[n1];
    int len = hi - lo;
    int mid = lo + (len >> 1);
    int s0 = half ? mid : lo;
    int s1 = half ? hi : mid;
    for (int i = s0 + threadIdx.x; i < s1; i += 256) {
        uint2 p = pairs[i];
        int pos = atomicAdd(&cursor[p.y], 1);
        col[pos] = (int)p.x;
    }
}

// h1' = (x @ W1) * dinv[node], bf16 out; 16 nodes/block, wave = 4 nodes x 16 lanes x 4 cols
__global__ void __launch_bounds__(256) gemm1_k(
        const float* __restrict__ x, const float* __restrict__ W1,
        const float* __restrict__ dinv, u16* __restrict__ hp, int n) {
    __shared__ float Wl[DIN * DH];
    __shared__ float xl[16][DIN + 4];
    int tid = threadIdx.x;
    {
        const float4* Wv = (const float4*)W1;
        float4* Wd = (float4*)Wl;
        Wd[tid] = Wv[tid];
        Wd[tid + 256] = Wv[tid + 256];
    }
    if (tid < 128) {
        int idx = tid * 4;
        int row = idx / DIN, ck = idx % DIN;
        float4 v = {0.f, 0.f, 0.f, 0.f};
        if (blockIdx.x * 16 + row < n)
            v = *(const float4*)&x[(size_t)blockIdx.x * 16 * DIN + idx];
        *(float4*)&xl[row][ck] = v;
    }
    __syncthreads();
    int lane = tid & 63, w = tid >> 6;
    int g = lane >> 4, c = lane & 15;
    int node = blockIdx.x * 16 + w * 4 + g;
    const float* xr = xl[w * 4 + g];
    float4 acc = {0.f, 0.f, 0.f, 0.f};
    #pragma unroll
    for (int k = 0; k < DIN; k++) {
        float xv = xr[k];
        float4 wv = *(const float4*)&Wl[k * DH + c * 4];
        acc.x += xv * wv.x; acc.y += xv * wv.y; acc.z += xv * wv.z; acc.w += xv * wv.w;
    }
    if (node < n) {
        float di = dinv[node];
        ushort4 o;
        o.x = f2bf(acc.x * di); o.y = f2bf(acc.y * di);
        o.z = f2bf(acc.z * di); o.w = f2bf(acc.w * di);
        *(ushort4*)&hp[(size_t)node * DH + c * 4] = o;
    }
}

// h2' = (relu(io) @ W2) * dinv[node], bf16 out
__global__ void __launch_bounds__(256) gemm2_k(
        const float* __restrict__ io, const float* __restrict__ W2,
        const float* __restrict__ dinv, u16* __restrict__ hp, int n) {
    __shared__ float Wl[DH * DH];
    __shared__ float xl[16][DH + 4];
    int tid = threadIdx.x;
    {
        const float4* Wv = (const float4*)W2;
        float4* Wd = (float4*)Wl;
        #pragma unroll
        for (int r = 0; r < 4; r++) Wd[tid + 256 * r] = Wv[tid + 256 * r];
    }
    {
        int idx = tid * 4;
        int row = idx / DH, ck = idx % DH;
        float4 v = {0.f, 0.f, 0.f, 0.f};
        if (blockIdx.x * 16 + row < n) {
            v = *(const float4*)&io[(size_t)blockIdx.x * 16 * DH + idx];
            v.x = fmaxf(v.x, 0.f); v.y = fmaxf(v.y, 0.f);
            v.z = fmaxf(v.z, 0.f); v.w = fmaxf(v.w, 0.f);
        }
        *(float4*)&xl[row][ck] = v;
    }
    __syncthreads();
    int lane = tid & 63, w = tid >> 6;
    int g = lane >> 4, c = lane & 15;
    int node = blockIdx.x * 16 + w * 4 + g;
    const float* xr = xl[w * 4 + g];
    float4 acc = {0.f, 0.f, 0.f, 0.f};
    #pragma unroll
    for (int k = 0; k < DH; k++) {
        float xv = xr[k];
        float4 wv = *(const float4*)&Wl[k * DH + c * 4];
        acc.x += xv * wv.x; acc.y += xv * wv.y; acc.z += xv * wv.z; acc.w += xv * wv.w;
    }
    if (node < n) {
        float di = dinv[node];
        ushort4 o;
        o.x = f2bf(acc.x * di); o.y = f2bf(acc.y * di);
        o.z = f2bf(acc.z * di); o.w = f2bf(acc.w * di);
        *(ushort4*)&hp[(size_t)node * DH + c * 4] = o;
    }
}

// edge-sum core over bf16 rows: wave = 1 node; g=lane>>4 (edge slot), c=lane&15 (4 cols)
__device__ __forceinline__ float4 edge_sum(const u16* __restrict__ hp,
                                           const int* __restrict__ rowptr,
                                           const int* __restrict__ col,
                                           int node, int g, int c) {
    int start = __builtin_amdgcn_readfirstlane(rowptr[node]);
    int end   = __builtin_amdgcn_readfirstlane(rowptr[node + 1]);
    int lane  = (g << 4) | c;
    float4 acc = {0.f, 0.f, 0.f, 0.f};
    for (int base = start; base < end; base += 64) {
        int rem = end - base; if (rem > 64) rem = 64;
        int cb = (lane < rem) ? col[base + lane] : 0;
        for (int jj = 0; jj < rem; jj += 8) {
            int e0 = jj + g, e1 = jj + 4 + g;
            int s0 = __shfl(cb, e0, 64);
            int s1 = __shfl(cb, e1, 64);
            bool a0 = e0 < rem, a1 = e1 < rem;
            if (a0) {
                ushort4 v = *(const ushort4*)&hp[(size_t)s0 * DH + c * 4];
                acc.x += bf2f(v.x); acc.y += bf2f(v.y); acc.z += bf2f(v.z); acc.w += bf2f(v.w);
            }
            if (a1) {
                ushort4 v = *(const ushort4*)&hp[(size_t)s1 * DH + c * 4];
                acc.x += bf2f(v.x); acc.y += bf2f(v.y); acc.z += bf2f(v.z); acc.w += bf2f(v.w);
            }
        }
    }
    #pragma unroll
    for (int m = 16; m <= 32; m <<= 1) {
        acc.x += __shfl_xor(acc.x, m, 64);
        acc.y += __shfl_xor(acc.y, m, 64);
        acc.z += __shfl_xor(acc.z, m, 64);
        acc.w += __shfl_xor(acc.w, m, 64);
    }
    return acc;
}

// out[d] = (h'[d] + sum_neighbors) * dinv[d] + bias   (fp32 out)
__global__ void __launch_bounds__(256) agg_mid_k(
        const u16* __restrict__ hp, const int* __restrict__ rowptr,
        const int* __restrict__ col, const float* __restrict__ dinv,
        const float* __restrict__ bias, float* __restrict__ out, int N) {
    int lane = threadIdx.x & 63;
    int node = blockIdx.x * 4 + (threadIdx.x >> 6);
    if (node >= N) return;
    int g = lane >> 4, c = lane & 15;
    float4 acc = edge_sum(hp, rowptr, col, node, g, c);
    if (g == 0) {
        ushort4 sv = *(const ushort4*)&hp[(size_t)node * DH + c * 4];
        float4 b = *(const float4*)&bias[c * 4];
        float di = dinv[node];
        float4 o;
        o.x = (acc.x + bf2f(sv.x)) * di + b.x;
        o.y = (acc.y + bf2f(sv.y)) * di + b.y;
        o.z = (acc.z + bf2f(sv.z)) * di + b.z;
        o.w = (acc.w + bf2f(sv.w)) * di + b.w;
        *(float4*)&out[(size_t)node * DH + c * 4] = o;
    }
}

// fused layer-2 aggregation + head: y = sigmoid(relu(out2) . Wo + bo)
__global__ void __launch_bounds__(256) agg_head_k(
        const u16* __restrict__ hp, const int* __restrict__ rowptr,
        const int* __restrict__ col, const float* __restrict__ dinv,
        const float* __restrict__ bias, const float* __restrict__ Wo,
        const float* __restrict__ bo, float* __restrict__ y, int N) {
    int lane = threadIdx.x & 63;
    int node = blockIdx.x * 4 + (threadIdx.x >> 6);
    if (node >= N) return;
    int g = lane >> 4, c = lane & 15;
    float4 acc = edge_sum(hp, rowptr, col, node, g, c);
    if (g == 0) {
        ushort4 sv = *(const ushort4*)&hp[(size_t)node * DH + c * 4];
        float4 b = *(const float4*)&bias[c * 4];
        float4 wo = *(const float4*)&Wo[c * 4];
        float di = dinv[node];
        float t = fmaxf((acc.x + bf2f(sv.x)) * di + b.x, 0.f) * wo.x
                + fmaxf((acc.y + bf2f(sv.y)) * di + b.y, 0.f) * wo.y
                + fmaxf((acc.z + bf2f(sv.z)) * di + b.z, 0.f) * wo.z
                + fmaxf((acc.w + bf2f(sv.w)) * di + b.w, 0.f) * wo.w;
        #pragma unroll
        for (int m = 1; m < 16; m <<= 1) t += __shfl_xor(t, m, 64);
        if (c == 0) {
            float z = t + bo[0];
            y[node] = 1.f / (1.f + __expf(-z));
        }
    }
}

extern "C" void kernel_launch(void* const* d_in, const int* in_sizes, int n_in,
                              void* d_out, int out_size, void* d_ws, size_t ws_size,
                              hipStream_t stream) {
    const float* x  = (const float*)d_in[0];
    const int*   ei = (const int*)d_in[1];
    const float* W1 = (const float*)d_in[2];
    const float* b1 = (const float*)d_in[3];
    const float* W2 = (const float*)d_in[4];
    const float* b2 = (const float*)d_in[5];
    const float* Wo = (const float*)d_in[6];
    const float* bo = (const float*)d_in[7];
    float* y = (float*)d_out;

    int N = in_sizes[0] / DIN;
    int E = in_sizes[1] / 2;

    char* ws = (char*)d_ws;
    size_t off = 0;
    auto alloc = [&](size_t bytes) { char* p = ws + off; off += (bytes + 255) & ~(size_t)255; return p; };
    int*   flag     = (int*)alloc(4);
    int*   cursor   = (int*)alloc((size_t)N * 4);            // doubles as cnt
    int*   rowptr   = (int*)alloc(((size_t)N + 1) * 4);
    int*   partials = (int*)alloc(256 * 4);
    int*   gcur     = (int*)alloc(MAXB * 4);
    float* dinv     = (float*)alloc((size_t)N * 4);
    int*   col      = (int*)alloc((size_t)E * 4);
    char*  bufA     = (char*)alloc((size_t)N * DH * 4);      // bf16 hp (12.8MB) / pairs alias
    float* bufB     = (float*)alloc((size_t)N * DH * 4);     // fp32 out1
    u16*   hp    = (u16*)bufA;
    uint2* pairs = (uint2*)bufA;   // pairs (E*8B) dead before gemm1 writes hp

    int gN   = (N + 255) / 256;
    int gE   = (E + 255) / 256;
    int gN4  = (N + 3) / 4;
    int gN16 = (N + 15) / 16;
    int nb   = (N + 1023) / 1024;
    int nbuck = ((N - 1) >> BSH) + 1;            // 49 for N=100k (<= MAXB)

    edge_mode_k<<<1, 256, 0, stream>>>(ei, E, flag);
    hipMemsetAsync(cursor, 0, (size_t)N * 4, stream);
    hist_k<<<gE, 256, 0, stream>>>(ei, flag, cursor, E, N);
    scan1_k<<<nb, 256, 0, stream>>>(cursor, rowptr, partials, N);
    scan2_k<<<1, 256, 0, stream>>>(partials, rowptr + N, nb);
    scan3_k<<<gN, 256, 0, stream>>>(rowptr, cursor, partials, dinv, N);
    initgcur_k<<<(nbuck + 255) / 256, 256, 0, stream>>>(rowptr, gcur, nbuck, N);
    binA_k<<<256, 256, 0, stream>>>(ei, flag, gcur, pairs, E, N, nbuck);
    fillB_k<<<2 * nbuck, 256, 0, stream>>>(pairs, rowptr, cursor, col, N);

    // layer 1
    gemm1_k<<<gN16, 256, 0, stream>>>(x, W1, dinv, hp, N);
    agg_mid_k<<<gN4, 256, 0, stream>>>(hp, rowptr, col, dinv, b1, bufB, N);

    // layer 2 + fused head
    gemm2_k<<<gN16, 256, 0, stream>>>(bufB, W2, dinv, hp, N);
    agg_head_k<<<gN4, 256, 0, stream>>>(hp, rowptr, col, dinv, b2, Wo, bo, y, N);
}

// Round 6
// 277.169 us; speedup vs baseline: 3.4521x; 1.3667x over previous
//
#include <hip/hip_runtime.h>

#define DH 64
#define DIN 32
#define BSH 9                 // bucket = dst >> 9 (512-node ranges)
#define BNODES 512
#define MAXB 1024

typedef unsigned short u16;
typedef unsigned int u32;

__device__ __forceinline__ float bf2f(u16 u) {
    union { unsigned int i; float f; } x; x.i = ((unsigned int)u) << 16; return x.f;
}
__device__ __forceinline__ u16 f2bf(float f) {
    union { float f; unsigned int i; } x; x.f = f;
    unsigned int r = x.i + 0x7fff + ((x.i >> 16) & 1);   // round-to-nearest-even
    return (u16)(r >> 16);
}

// ---- edge layout probe: 1 = int32 layout, 0 = int64 (values in low words, stride 2)
__global__ void edge_mode_k(const int* __restrict__ ei, int E, int* __restrict__ flag) {
    __shared__ int any;
    if (threadIdx.x == 0) any = 0;
    __syncthreads();
    int i = threadIdx.x;
    int lim = (E < 512) ? E : 512;
    int v = (2 * i + 1 < 2 * lim) ? ei[2 * i + 1] : 0;
    if (v != 0) atomicOr(&any, 1);
    __syncthreads();
    if (threadIdx.x == 0) *flag = any;
}

// per-bucket edge counts (gbucket pre-zeroed); one global atomic per (block,bucket)
__global__ void __launch_bounds__(256) bucket_count_k(
        const int* __restrict__ ei, const int* __restrict__ flag,
        int* __restrict__ gbucket, int E, int n, int nbuck) {
    __shared__ int lh[MAXB];
    int t = threadIdx.x;
    for (int b = t; b < nbuck; b += 256) lh[b] = 0;
    __syncthreads();
    int m = *flag;
    const int* dstp = m ? (ei + E) : (ei + 2 * E);
    int stride = m ? 1 : 2;
    int chunk = (E + gridDim.x - 1) / gridDim.x;
    int lo = blockIdx.x * chunk;
    int hi = lo + chunk; if (hi > E) hi = E;
    for (int e = lo + t; e < hi; e += 256) {
        int d = dstp[(size_t)e * stride];
        if ((unsigned)d < (unsigned)n) atomicAdd(&lh[d >> BSH], 1);
    }
    __syncthreads();
    for (int b = t; b < nbuck; b += 256) if (lh[b]) atomicAdd(&gbucket[b], lh[b]);
}

// single-block scan of bucket totals -> bucket_base[0..nbuck], gcur init, rowptr[N]
__global__ void __launch_bounds__(256) bucket_scan_k(
        const int* __restrict__ gbucket, int* __restrict__ bucket_base,
        int* __restrict__ gcur, int* __restrict__ rowptr_end, int nbuck) {
    __shared__ int s[256];
    int t = threadIdx.x;
    int b0 = t * 4;
    int v0 = (b0 + 0 < nbuck) ? gbucket[b0 + 0] : 0;
    int v1 = (b0 + 1 < nbuck) ? gbucket[b0 + 1] : 0;
    int v2 = (b0 + 2 < nbuck) ? gbucket[b0 + 2] : 0;
    int v3 = (b0 + 3 < nbuck) ? gbucket[b0 + 3] : 0;
    int tot = v0 + v1 + v2 + v3;
    s[t] = tot;
    __syncthreads();
    for (int off = 1; off < 256; off <<= 1) {
        int x = (t >= off) ? s[t - off] : 0;
        __syncthreads();
        s[t] += x;
        __syncthreads();
    }
    int excl = s[t] - tot;
    int e0 = excl, e1 = excl + v0, e2 = e1 + v1, e3 = e2 + v2;
    if (b0 + 0 < nbuck) { bucket_base[b0 + 0] = e0; gcur[b0 + 0] = e0; }
    if (b0 + 1 < nbuck) { bucket_base[b0 + 1] = e1; gcur[b0 + 1] = e1; }
    if (b0 + 2 < nbuck) { bucket_base[b0 + 2] = e2; gcur[b0 + 2] = e2; }
    if (b0 + 3 < nbuck) { bucket_base[b0 + 3] = e3; gcur[b0 + 3] = e3; }
    if (t == 255) { bucket_base[nbuck] = s[255]; *rowptr_end = s[255]; }
}

// bin packed (src<<BSH | local_dst) into bucket-contiguous pairs[] with
// per-(block,bucket) private spans -> partial lines assembled in one L2 each
__global__ void __launch_bounds__(256) binA_k(
        const int* __restrict__ ei, const int* __restrict__ flag,
        int* __restrict__ gcur, u32* __restrict__ pairs, int E, int n, int nbuck) {
    __shared__ int lhist[MAXB];
    __shared__ int lbase[MAXB];
    int t = threadIdx.x;
    for (int b = t; b < nbuck; b += 256) lhist[b] = 0;
    __syncthreads();
    int m = *flag;
    const int* srcp = ei;
    const int* dstp = m ? (ei + E) : (ei + 2 * E);
    int stride = m ? 1 : 2;
    int chunk = (E + gridDim.x - 1) / gridDim.x;
    int lo = blockIdx.x * chunk;
    int hi = lo + chunk; if (hi > E) hi = E;
    for (int e = lo + t; e < hi; e += 256) {
        int d = dstp[(size_t)e * stride];
        if ((unsigned)d < (unsigned)n) atomicAdd(&lhist[d >> BSH], 1);
    }
    __syncthreads();
    for (int b = t; b < nbuck; b += 256) {
        int c = lhist[b];
        lbase[b] = c ? atomicAdd(&gcur[b], c) : 0;
        lhist[b] = 0;                       // reuse as local cursor
    }
    __syncthreads();
    for (int e = lo + t; e < hi; e += 256) {
        int d = dstp[(size_t)e * stride];
        if ((unsigned)d >= (unsigned)n) continue;
        int s = srcp[(size_t)e * stride];
        if ((unsigned)s >= (unsigned)n) s = 0;
        int b = d >> BSH;
        int off = atomicAdd(&lhist[b], 1);
        pairs[lbase[b] + off] = ((u32)s << BSH) | (u32)(d & (BNODES - 1));
    }
}

// one block per bucket: LDS per-node histogram + scan -> rowptr/dinv, then fill col
__global__ void __launch_bounds__(256) csr_bucket_k(
        const u32* __restrict__ pairs, const int* __restrict__ bucket_base,
        int* __restrict__ rowptr, int* __restrict__ col, float* __restrict__ dinv, int N) {
    __shared__ int cnt[BNODES];
    __shared__ int s[256];
    int b = blockIdx.x, t = threadIdx.x;
    int base = bucket_base[b], end = bucket_base[b + 1];
    cnt[t] = 0; cnt[t + 256] = 0;
    __syncthreads();
    for (int i = base + t; i < end; i += 256)
        atomicAdd(&cnt[pairs[i] & (BNODES - 1)], 1);
    __syncthreads();
    int v0 = cnt[2 * t], v1 = cnt[2 * t + 1];
    int tot = v0 + v1;
    s[t] = tot;
    __syncthreads();
    for (int off = 1; off < 256; off <<= 1) {
        int x = (t >= off) ? s[t - off] : 0;
        __syncthreads();
        s[t] += x;
        __syncthreads();
    }
    int excl = s[t] - tot;
    int a0 = base + excl, a1 = a0 + v0;
    int n0 = (b << BSH) + 2 * t, n1 = n0 + 1;
    if (n0 < N) { rowptr[n0] = a0; dinv[n0] = rsqrtf((float)v0 + 1.0f); }
    if (n1 < N) { rowptr[n1] = a1; dinv[n1] = rsqrtf((float)v1 + 1.0f); }
    cnt[2 * t] = a0; cnt[2 * t + 1] = a1;   // only owner thread touched these
    __syncthreads();
    for (int i = base + t; i < end; i += 256) {
        u32 p = pairs[i];
        int pos = atomicAdd(&cnt[p & (BNODES - 1)], 1);
        col[pos] = (int)(p >> BSH);
    }
}

// h1' = (x @ W1) * dinv[node], bf16 out; 16 nodes/block, wave = 4 nodes x 16 lanes x 4 cols
__global__ void __launch_bounds__(256) gemm1_k(
        const float* __restrict__ x, const float* __restrict__ W1,
        const float* __restrict__ dinv, u16* __restrict__ hp, int n) {
    __shared__ float Wl[DIN * DH];
    __shared__ float xl[16][DIN + 4];
    int tid = threadIdx.x;
    {
        const float4* Wv = (const float4*)W1;
        float4* Wd = (float4*)Wl;
        Wd[tid] = Wv[tid];
        Wd[tid + 256] = Wv[tid + 256];
    }
    if (tid < 128) {
        int idx = tid * 4;
        int row = idx / DIN, ck = idx % DIN;
        float4 v = {0.f, 0.f, 0.f, 0.f};
        if (blockIdx.x * 16 + row < n)
            v = *(const float4*)&x[(size_t)blockIdx.x * 16 * DIN + idx];
        *(float4*)&xl[row][ck] = v;
    }
    __syncthreads();
    int lane = tid & 63, w = tid >> 6;
    int g = lane >> 4, c = lane & 15;
    int node = blockIdx.x * 16 + w * 4 + g;
    const float* xr = xl[w * 4 + g];
    float4 acc = {0.f, 0.f, 0.f, 0.f};
    #pragma unroll
    for (int k = 0; k < DIN; k++) {
        float xv = xr[k];
        float4 wv = *(const float4*)&Wl[k * DH + c * 4];
        acc.x += xv * wv.x; acc.y += xv * wv.y; acc.z += xv * wv.z; acc.w += xv * wv.w;
    }
    if (node < n) {
        float di = dinv[node];
        ushort4 o;
        o.x = f2bf(acc.x * di); o.y = f2bf(acc.y * di);
        o.z = f2bf(acc.z * di); o.w = f2bf(acc.w * di);
        *(ushort4*)&hp[(size_t)node * DH + c * 4] = o;
    }
}

// h2' = (relu(out1_bf16) @ W2) * dinv[node], bf16 out
__global__ void __launch_bounds__(256) gemm2_k(
        const u16* __restrict__ io, const float* __restrict__ W2,
        const float* __restrict__ dinv, u16* __restrict__ hp, int n) {
    __shared__ float Wl[DH * DH];
    __shared__ float xl[16][DH + 4];
    int tid = threadIdx.x;
    {
        const float4* Wv = (const float4*)W2;
        float4* Wd = (float4*)Wl;
        #pragma unroll
        for (int r = 0; r < 4; r++) Wd[tid + 256 * r] = Wv[tid + 256 * r];
    }
    {
        int idx = tid * 4;
        int row = idx / DH, ck = idx % DH;
        float4 v = {0.f, 0.f, 0.f, 0.f};
        if (blockIdx.x * 16 + row < n) {
            ushort4 u = *(const ushort4*)&io[(size_t)blockIdx.x * 16 * DH + idx];
            v.x = fmaxf(bf2f(u.x), 0.f); v.y = fmaxf(bf2f(u.y), 0.f);
            v.z = fmaxf(bf2f(u.z), 0.f); v.w = fmaxf(bf2f(u.w), 0.f);
        }
        *(float4*)&xl[row][ck] = v;
    }
    __syncthreads();
    int lane = tid & 63, w = tid >> 6;
    int g = lane >> 4, c = lane & 15;
    int node = blockIdx.x * 16 + w * 4 + g;
    const float* xr = xl[w * 4 + g];
    float4 acc = {0.f, 0.f, 0.f, 0.f};
    #pragma unroll
    for (int k = 0; k < DH; k++) {
        float xv = xr[k];
        float4 wv = *(const float4*)&Wl[k * DH + c * 4];
        acc.x += xv * wv.x; acc.y += xv * wv.y; acc.z += xv * wv.z; acc.w += xv * wv.w;
    }
    if (node < n) {
        float di = dinv[node];
        ushort4 o;
        o.x = f2bf(acc.x * di); o.y = f2bf(acc.y * di);
        o.z = f2bf(acc.z * di); o.w = f2bf(acc.w * di);
        *(ushort4*)&hp[(size_t)node * DH + c * 4] = o;
    }
}

// edge-sum core over bf16 rows: wave = 1 node; g=lane>>4 (edge slot), c=lane&15 (4 cols)
__device__ __forceinline__ float4 edge_sum(const u16* __restrict__ hp,
                                           const int* __restrict__ rowptr,
                                           const int* __restrict__ col,
                                           int node, int g, int c) {
    int start = __builtin_amdgcn_readfirstlane(rowptr[node]);
    int end   = __builtin_amdgcn_readfirstlane(rowptr[node + 1]);
    int lane  = (g << 4) | c;
    float4 acc = {0.f, 0.f, 0.f, 0.f};
    for (int base = start; base < end; base += 64) {
        int rem = end - base; if (rem > 64) rem = 64;
        int cb = (lane < rem) ? col[base + lane] : 0;
        for (int jj = 0; jj < rem; jj += 8) {
            int e0 = jj + g, e1 = jj + 4 + g;
            int s0 = __shfl(cb, e0, 64);
            int s1 = __shfl(cb, e1, 64);
            bool a0 = e0 < rem, a1 = e1 < rem;
            if (a0) {
                ushort4 v = *(const ushort4*)&hp[(size_t)s0 * DH + c * 4];
                acc.x += bf2f(v.x); acc.y += bf2f(v.y); acc.z += bf2f(v.z); acc.w += bf2f(v.w);
            }
            if (a1) {
                ushort4 v = *(const ushort4*)&hp[(size_t)s1 * DH + c * 4];
                acc.x += bf2f(v.x); acc.y += bf2f(v.y); acc.z += bf2f(v.z); acc.w += bf2f(v.w);
            }
        }
    }
    #pragma unroll
    for (int m = 16; m <= 32; m <<= 1) {
        acc.x += __shfl_xor(acc.x, m, 64);
        acc.y += __shfl_xor(acc.y, m, 64);
        acc.z += __shfl_xor(acc.z, m, 64);
        acc.w += __shfl_xor(acc.w, m, 64);
    }
    return acc;
}

// out1[d] = (h'[d] + sum_neighbors) * dinv[d] + bias  -> bf16
__global__ void __launch_bounds__(256) agg_mid_k(
        const u16* __restrict__ hp, const int* __restrict__ rowptr,
        const int* __restrict__ col, const float* __restrict__ dinv,
        const float* __restrict__ bias, u16* __restrict__ out, int N) {
    int lane = threadIdx.x & 63;
    int node = blockIdx.x * 4 + (threadIdx.x >> 6);
    if (node >= N) return;
    int g = lane >> 4, c = lane & 15;
    float4 acc = edge_sum(hp, rowptr, col, node, g, c);
    if (g == 0) {
        ushort4 sv = *(const ushort4*)&hp[(size_t)node * DH + c * 4];
        float4 b = *(const float4*)&bias[c * 4];
        float di = dinv[node];
        ushort4 o;
        o.x = f2bf((acc.x + bf2f(sv.x)) * di + b.x);
        o.y = f2bf((acc.y + bf2f(sv.y)) * di + b.y);
        o.z = f2bf((acc.z + bf2f(sv.z)) * di + b.z);
        o.w = f2bf((acc.w + bf2f(sv.w)) * di + b.w);
        *(ushort4*)&out[(size_t)node * DH + c * 4] = o;
    }
}

// fused layer-2 aggregation + head: y = sigmoid(relu(out2) . Wo + bo)
__global__ void __launch_bounds__(256) agg_head_k(
        const u16* __restrict__ hp, const int* __restrict__ rowptr,
        const int* __restrict__ col, const float* __restrict__ dinv,
        const float* __restrict__ bias, const float* __restrict__ Wo,
        const float* __restrict__ bo, float* __restrict__ y, int N) {
    int lane = threadIdx.x & 63;
    int node = blockIdx.x * 4 + (threadIdx.x >> 6);
    if (node >= N) return;
    int g = lane >> 4, c = lane & 15;
    float4 acc = edge_sum(hp, rowptr, col, node, g, c);
    if (g == 0) {
        ushort4 sv = *(const ushort4*)&hp[(size_t)node * DH + c * 4];
        float4 b = *(const float4*)&bias[c * 4];
        float4 wo = *(const float4*)&Wo[c * 4];
        float di = dinv[node];
        float t = fmaxf((acc.x + bf2f(sv.x)) * di + b.x, 0.f) * wo.x
                + fmaxf((acc.y + bf2f(sv.y)) * di + b.y, 0.f) * wo.y
                + fmaxf((acc.z + bf2f(sv.z)) * di + b.z, 0.f) * wo.z
                + fmaxf((acc.w + bf2f(sv.w)) * di + b.w, 0.f) * wo.w;
        #pragma unroll
        for (int m = 1; m < 16; m <<= 1) t += __shfl_xor(t, m, 64);
        if (c == 0) {
            float z = t + bo[0];
            y[node] = 1.f / (1.f + __expf(-z));
        }
    }
}

extern "C" void kernel_launch(void* const* d_in, const int* in_sizes, int n_in,
                              void* d_out, int out_size, void* d_ws, size_t ws_size,
                              hipStream_t stream) {
    const float* x  = (const float*)d_in[0];
    const int*   ei = (const int*)d_in[1];
    const float* W1 = (const float*)d_in[2];
    const float* b1 = (const float*)d_in[3];
    const float* W2 = (const float*)d_in[4];
    const float* b2 = (const float*)d_in[5];
    const float* Wo = (const float*)d_in[6];
    const float* bo = (const float*)d_in[7];
    float* y = (float*)d_out;

    int N = in_sizes[0] / DIN;
    int E = in_sizes[1] / 2;

    char* ws = (char*)d_ws;
    size_t off = 0;
    auto alloc = [&](size_t bytes) { char* p = ws + off; off += (bytes + 255) & ~(size_t)255; return p; };
    int*   flag        = (int*)alloc(4);
    int*   gbucket     = (int*)alloc(MAXB * 4);
    int*   bucket_base = (int*)alloc((MAXB + 1) * 4);
    int*   gcur        = (int*)alloc(MAXB * 4);
    int*   rowptr      = (int*)alloc(((size_t)N + 1) * 4);
    float* dinv        = (float*)alloc((size_t)N * 4);
    int*   col         = (int*)alloc((size_t)E * 4);
    char*  bufA        = (char*)alloc((size_t)N * DH * 2);   // hp bf16 (12.8MB) / pairs alias
    u16*   bufB        = (u16*)alloc((size_t)N * DH * 2);    // out1 bf16
    u16*   hp    = (u16*)bufA;
    u32*   pairs = (u32*)bufA;   // pairs (E*4B=6.4MB) dead before gemm1 writes hp

    int gN4  = (N + 3) / 4;
    int gN16 = (N + 15) / 16;
    int nbuck = ((N - 1) >> BSH) + 1;            // 196 for N=100k (<= MAXB)

    edge_mode_k<<<1, 256, 0, stream>>>(ei, E, flag);
    hipMemsetAsync(gbucket, 0, (size_t)nbuck * 4, stream);
    bucket_count_k<<<256, 256, 0, stream>>>(ei, flag, gbucket, E, N, nbuck);
    bucket_scan_k<<<1, 256, 0, stream>>>(gbucket, bucket_base, gcur, rowptr + N, nbuck);
    binA_k<<<256, 256, 0, stream>>>(ei, flag, gcur, pairs, E, N, nbuck);
    csr_bucket_k<<<nbuck, 256, 0, stream>>>(pairs, bucket_base, rowptr, col, dinv, N);

    // layer 1
    gemm1_k<<<gN16, 256, 0, stream>>>(x, W1, dinv, hp, N);
    agg_mid_k<<<gN4, 256, 0, stream>>>(hp, rowptr, col, dinv, b1, bufB, N);

    // layer 2 + fused head
    gemm2_k<<<gN16, 256, 0, stream>>>(bufB, W2, dinv, hp, N);
    agg_head_k<<<gN4, 256, 0, stream>>>(hp, rowptr, col, dinv, b2, Wo, bo, y, N);
}